// Round 8
// baseline (43.424 us; speedup 1.0000x reference)
//
#include <hip/hip_runtime.h>
#include <hip/hip_bf16.h>
#include <math.h>

// Problem constants
#define CIN 64
#define CQK 8
#define BATCH 8
#define NPOS 4096   // H*W
#define TN 128      // n-tile
#define NT (NPOS / TN)

typedef __attribute__((ext_vector_type(8))) short s16x8;
typedef __attribute__((ext_vector_type(4))) float f32x4;
typedef __attribute__((ext_vector_type(16))) float f32x16;

#define Z16 {0,0,0,0,0,0,0,0,0,0,0,0,0,0,0,0}

// single-instruction packed f32->bf16 (RNE) pair convert
__device__ inline unsigned cvt_pk_bf16(float lo, float hi) {
    unsigned r;
    asm("v_cvt_pk_bf16_f32 %0, %1, %2" : "=v"(r) : "v"(lo), "v"(hi));
    return r;
}

// ---------------------------------------------------------------------------
// Kernel 1: MFMA projections -> bf16.
//   One x-fragment pair serves BOTH as B-operand (KQ tile: A=W, D=[oc][n])
//   and as A-operand (V tiles: B=W, D=[n][C]) since A/B lane mappings of
//   mfma_f32_16x16x32_bf16 coincide (row/col=l&15, k=(l>>4)*8+e).
//   Outputs:
//     Kp[b,n,o] (o<8)           keys   (Wf + bf)
//     Qp[b,n,o] (o<8, *log2e)   queries(Wg + bg), pre-scaled for log2-domain
//     Vimg      values (Wh + bh) written DIRECTLY in the attention image
//               layout: piece p = ((j&1)*2+(C>>5))*64 + (j>>1)*32 + (C&31),
//               j = (h&1)*2 + (w&1), half = h>>1 (validated layout, round 6).
// Block = 256 thr (4 waves), 64 n; wave w owns n-group w*16..w*16+15.
// ---------------------------------------------------------------------------
__global__ __launch_bounds__(256) void proj_kernel(
    const float* __restrict__ x,
    const float* __restrict__ Wf, const float* __restrict__ bf,
    const float* __restrict__ Wg, const float* __restrict__ bg,
    const float* __restrict__ Wh, const float* __restrict__ bh,
    unsigned short* __restrict__ Kp, unsigned short* __restrict__ Qp,
    unsigned short* __restrict__ Vimg)
{
    __shared__ float xs[CIN * 66];   // 16.9 KB; stride 66 -> frag reads 2/bank
    __shared__ float bss[80];        // bf(8) | bg(8) | bh(64)

    const int tid = threadIdx.x;
    const int b   = blockIdx.y;
    const int n0  = blockIdx.x * 64;

    if (tid < 80)
        bss[tid] = (tid < 8) ? bf[tid] : (tid < 16) ? bg[tid - 8] : bh[tid - 16];

    // ---- stage x tile (64c x 64n f32), coalesced global, float2 LDS ----
    {
        const int c   = tid >> 2;
        const int seg = tid & 3;
        const float* src = x + ((size_t)(b * CIN + c)) * NPOS + n0 + seg * 16;
        float* dst = xs + c * 66 + seg * 16;
#pragma unroll
        for (int k = 0; k < 4; ++k) {
            const float4 v = *(const float4*)(src + k * 4);
            *(float2*)(dst + k * 4)     = make_float2(v.x, v.y);
            *(float2*)(dst + k * 4 + 2) = make_float2(v.z, v.w);
        }
    }

    const int l  = tid & 63;
    const int w  = tid >> 6;       // wave = n-group
    const int lm = l & 15;
    const int h  = l >> 4;

    // ---- W fragments (each lane: 8 consecutive c of one row/col) ----
    auto wfrag = [&](const float* Wrow) -> s16x8 {
        const float4 a  = *(const float4*)(Wrow);
        const float4 bq = *(const float4*)(Wrow + 4);
        union { unsigned u[4]; s16x8 v; } r;
        r.u[0] = cvt_pk_bf16(a.x, a.y);
        r.u[1] = cvt_pk_bf16(a.z, a.w);
        r.u[2] = cvt_pk_bf16(bq.x, bq.y);
        r.u[3] = cvt_pk_bf16(bq.z, bq.w);
        return r.v;
    };

    const float* kqrow = (lm < 8) ? (Wf + lm * CIN) : (Wg + (lm - 8) * CIN);
    const s16x8 wkq0 = wfrag(kqrow + h * 8);
    const s16x8 wkq1 = wfrag(kqrow + h * 8 + 32);
    s16x8 wv0[4], wv1[4];
#pragma unroll
    for (int vt = 0; vt < 4; ++vt) {
        const float* vr = Wh + (vt * 16 + lm) * CIN + h * 8;
        wv0[vt] = wfrag(vr);
        wv1[vt] = wfrag(vr + 32);
    }

    __syncthreads();

    // ---- x fragments: col/row n = lm, k-slots c = h*8+e (+32 for half1) ----
    union { unsigned u[4]; s16x8 v; } xf0, xf1;
#pragma unroll
    for (int e2 = 0; e2 < 4; ++e2) {
        const int c = h * 8 + e2 * 2;
        xf0.u[e2] = cvt_pk_bf16(xs[c * 66 + w * 16 + lm],
                                xs[(c + 1) * 66 + w * 16 + lm]);
        xf1.u[e2] = cvt_pk_bf16(xs[(c + 32) * 66 + w * 16 + lm],
                                xs[(c + 33) * 66 + w * 16 + lm]);
    }

    // ---- 10 MFMAs: 1 KQ tile + 4 V tiles, 2 k-halves each ----
    const f32x4 z = {0.f, 0.f, 0.f, 0.f};
    f32x4 kq = __builtin_amdgcn_mfma_f32_16x16x32_bf16(wkq0, xf0.v, z, 0, 0, 0);
    kq = __builtin_amdgcn_mfma_f32_16x16x32_bf16(wkq1, xf1.v, kq, 0, 0, 0);
    f32x4 va[4];
#pragma unroll
    for (int vt = 0; vt < 4; ++vt) {
        va[vt] = __builtin_amdgcn_mfma_f32_16x16x32_bf16(xf0.v, wv0[vt], z, 0, 0, 0);
        va[vt] = __builtin_amdgcn_mfma_f32_16x16x32_bf16(xf1.v, wv1[vt], va[vt], 0, 0, 0);
    }

    const float LOG2E = 1.44269504088896f;

    // ---- K/Q epilogue: D[col=n=lm][row=oc=h*4+j]; rows 0-7 K, 8-15 Q ----
    {
        const int n = n0 + w * 16 + lm;
        float v0 = kq[0] + bss[h * 4 + 0];
        float v1 = kq[1] + bss[h * 4 + 1];
        float v2 = kq[2] + bss[h * 4 + 2];
        float v3 = kq[3] + bss[h * 4 + 3];
        if (h >= 2) { v0 *= LOG2E; v1 *= LOG2E; v2 *= LOG2E; v3 *= LOG2E; }
        uint2 pk;
        pk.x = cvt_pk_bf16(v0, v1);
        pk.y = cvt_pk_bf16(v2, v3);
        unsigned short* dstq =
            (h < 2 ? Kp : Qp) + ((size_t)(b * NPOS + n)) * CQK + (h & 1) * 4;
        *(uint2*)dstq = pk;
    }

    // ---- V epilogue: D[col=C][row-quad h = n-quad]; direct image stores ----
    {
        const int t128 = n0 >> 7;
        const int sub  = ((n0 & 127) >> 5) + (w >> 1);
        unsigned short* dstB =
            Vimg + ((size_t)(b * 32 + t128)) * 8192 + (size_t)sub * 2048;
        const int jj   = (h & 1) * 2 + (w & 1);
        const int half = h >> 1;
#pragma unroll
        for (int vt = 0; vt < 4; ++vt) {
            const int C = vt * 16 + lm;
            const float bb = bss[16 + C];
            uint2 pk;
            pk.x = cvt_pk_bf16(va[vt][0] + bb, va[vt][1] + bb);
            pk.y = cvt_pk_bf16(va[vt][2] + bb, va[vt][3] + bb);
            const int p = ((jj & 1) * 2 + (C >> 5)) * 64 + (jj >> 1) * 32 + (C & 31);
            *(uint2*)(dstB + p * 8 + half * 4) = pk;
        }
    }
}

// ---------------------------------------------------------------------------
// Kernel 2: MFMA flash attention (unchanged structure from round 6; + T5
// s_setprio around the compute body). No-max unnormalized softmax, 32x32x16
// MFMA, no LDS in main loop, register double-buffer, counted vmcnt(5).
// ---------------------------------------------------------------------------
__global__ __launch_bounds__(256, 2) void attn_kernel(
    const unsigned short* __restrict__ Kp, const unsigned short* __restrict__ Qp,
    const unsigned short* __restrict__ Vimg, const float* __restrict__ x,
    const float* __restrict__ gamma, float* __restrict__ out)
{
    // epilogue only: 4 wave-regions x 64C x 36 f32 + 4x32 row sums
    __shared__ __align__(16) float smem[4 * 64 * 36 + 128];
    float* reg = smem;
    float* rsl = smem + 4 * 64 * 36;

    const int tid = threadIdx.x;
    const int l   = tid & 63;
    const int w   = tid >> 6;      // wave = substep owner
    const int lc  = l & 31;
    const int h   = l >> 5;
    const int id  = blockIdx.x;
    const int b   = id & 7;        // XCD-pinned batch
    const int m0  = (id >> 3) * 64;

    const unsigned short* Kbat = Kp + (size_t)b * NPOS * CQK;
    const char* Vbat = (const char*)(Vimg + (size_t)b * NPOS * CIN);

    // Q fragments (B operand): h=1 lanes (k=8..15) must be zero
    s16x8 qf0 = {0,0,0,0,0,0,0,0}, qf1 = {0,0,0,0,0,0,0,0};
    if (h == 0) {
        qf0 = *(const s16x8*)(Qp + ((size_t)(b * NPOS + m0 + lc)) * CQK);
        qf1 = *(const s16x8*)(Qp + ((size_t)(b * NPOS + m0 + 32 + lc)) * CQK);
    }

    f32x16 acc00 = Z16, acc01 = Z16, acc10 = Z16, acc11 = Z16;
    f32x16 rs0 = Z16, rs1 = Z16;
    const s16x8 vones = {0x3F80, 0x3F80, 0x3F80, 0x3F80,
                         0x3F80, 0x3F80, 0x3F80, 0x3F80};  // bf16 1.0

    s16x8 vfA[4], vfB[4], kaA, kaB;

    auto loadV = [&](s16x8* vf, int t) {
        const char* base = Vbat + (size_t)t * 16384 + w * 4096 + l * 16;
#pragma unroll
        for (int c = 0; c < 4; ++c)
            vf[c] = *(const s16x8*)(base + c * 1024);
    };
    auto loadK = [&](s16x8& kr, int t) {
        kr = *(const s16x8*)(Kbat + ((size_t)(t * TN + w * 32 + lc)) * CQK);
    };

    auto compute = [&](const s16x8& ka, const s16x8* vf) {
        __builtin_amdgcn_s_setprio(1);
        const f32x16 z = Z16;
        f32x16 sc0 = __builtin_amdgcn_mfma_f32_32x32x16_bf16(ka, qf0, z, 0, 0, 0);
        f32x16 sc1 = __builtin_amdgcn_mfma_f32_32x32x16_bf16(ka, qf1, z, 0, 0, 0);
        float p0[16], p1[16];
#pragma unroll
        for (int rr = 0; rr < 16; ++rr) {
            p0[rr] = __builtin_amdgcn_exp2f(sc0[rr]);
            p1[rr] = __builtin_amdgcn_exp2f(sc1[rr]);
        }
        union { unsigned u[4]; s16x8 v; } A10, A20, A11, A21;
#pragma unroll
        for (int i = 0; i < 4; ++i) {
            A10.u[i] = cvt_pk_bf16(p0[2 * i], p0[2 * i + 1]);
            A20.u[i] = cvt_pk_bf16(p0[8 + 2 * i], p0[9 + 2 * i]);
            A11.u[i] = cvt_pk_bf16(p1[2 * i], p1[2 * i + 1]);
            A21.u[i] = cvt_pk_bf16(p1[8 + 2 * i], p1[9 + 2 * i]);
        }
        rs0 = __builtin_amdgcn_mfma_f32_32x32x16_bf16(A10.v, vones, rs0, 0, 0, 0);
        rs0 = __builtin_amdgcn_mfma_f32_32x32x16_bf16(A20.v, vones, rs0, 0, 0, 0);
        rs1 = __builtin_amdgcn_mfma_f32_32x32x16_bf16(A11.v, vones, rs1, 0, 0, 0);
        rs1 = __builtin_amdgcn_mfma_f32_32x32x16_bf16(A21.v, vones, rs1, 0, 0, 0);
        acc00 = __builtin_amdgcn_mfma_f32_32x32x16_bf16(A10.v, vf[0], acc00, 0, 0, 0);
        acc00 = __builtin_amdgcn_mfma_f32_32x32x16_bf16(A20.v, vf[2], acc00, 0, 0, 0);
        acc01 = __builtin_amdgcn_mfma_f32_32x32x16_bf16(A10.v, vf[1], acc01, 0, 0, 0);
        acc01 = __builtin_amdgcn_mfma_f32_32x32x16_bf16(A20.v, vf[3], acc01, 0, 0, 0);
        acc10 = __builtin_amdgcn_mfma_f32_32x32x16_bf16(A11.v, vf[0], acc10, 0, 0, 0);
        acc10 = __builtin_amdgcn_mfma_f32_32x32x16_bf16(A21.v, vf[2], acc10, 0, 0, 0);
        acc11 = __builtin_amdgcn_mfma_f32_32x32x16_bf16(A11.v, vf[1], acc11, 0, 0, 0);
        acc11 = __builtin_amdgcn_mfma_f32_32x32x16_bf16(A21.v, vf[3], acc11, 0, 0, 0);
        __builtin_amdgcn_s_setprio(0);
    };

    loadV(vfA, 0); loadK(kaA, 0);
    loadV(vfB, 1); loadK(kaB, 1);

#pragma unroll 1
    for (int t = 0; t < NT; t += 2) {
        asm volatile("s_waitcnt vmcnt(5)" ::: "memory");   // tile t ready
        compute(kaA, vfA);
        if (t + 2 < NT) {
            loadV(vfA, t + 2); loadK(kaA, t + 2);
            asm volatile("s_waitcnt vmcnt(5)" ::: "memory"); // tile t+1 ready
        } else {
            asm volatile("s_waitcnt vmcnt(0)" ::: "memory");
        }
        compute(kaB, vfB);
        if (t + 3 < NT) { loadV(vfB, t + 3); loadK(kaB, t + 3); }
    }

    // ---- two-phase epilogue: combine wave partials per m-tile ----
    const float gm = gamma[0];
    auto epi = [&](const f32x16& a0, const f32x16& a1, const f32x16& rsv,
                   int mOff) {
#pragma unroll
        for (int rq = 0; rq < 4; ++rq) {
            const int mb = 8 * rq + 4 * h;
            const f32x4 q0 = {a0[4 * rq], a0[4 * rq + 1], a0[4 * rq + 2], a0[4 * rq + 3]};
            const f32x4 q1 = {a1[4 * rq], a1[4 * rq + 1], a1[4 * rq + 2], a1[4 * rq + 3]};
            *(f32x4*)(reg + w * 2304 + lc * 36 + mb)        = q0;  // C = lc
            *(f32x4*)(reg + w * 2304 + (32 + lc) * 36 + mb) = q1;  // C = 32+lc
            if (lc == 0) {
                const f32x4 qr = {rsv[4 * rq], rsv[4 * rq + 1], rsv[4 * rq + 2], rsv[4 * rq + 3]};
                *(f32x4*)(rsl + w * 32 + mb) = qr;
            }
        }
        __syncthreads();
        const int c  = tid >> 2;
        const int mq = tid & 3;
        const size_t base = ((size_t)(b * CIN + c)) * NPOS + m0 + mOff + mq * 8;
#pragma unroll
        for (int q4 = 0; q4 < 2; ++q4) {
            const float4 xv = *(const float4*)(x + base + q4 * 4);
            float4 o;
#pragma unroll
            for (int i = 0; i < 4; ++i) {
                const int ml = mq * 8 + q4 * 4 + i;
                const float rsum = (rsl[ml] + rsl[32 + ml]) + (rsl[64 + ml] + rsl[96 + ml]);
                const int oi = c * 36 + ml;
                const float os = (reg[oi] + reg[2304 + oi]) + (reg[4608 + oi] + reg[6912 + oi]);
                ((float*)&o)[i] = ((const float*)&xv)[i] + gm * os / rsum;
            }
            *(float4*)(out + base + q4 * 4) = o;
        }
        __syncthreads();
    };
    epi(acc00, acc01, rs0, 0);
    epi(acc10, acc11, rs1, 32);
}

extern "C" void kernel_launch(void* const* d_in, const int* in_sizes, int n_in,
                              void* d_out, int out_size, void* d_ws, size_t ws_size,
                              hipStream_t stream) {
    const float* x     = (const float*)d_in[0];
    const float* Wf    = (const float*)d_in[1];
    const float* bf    = (const float*)d_in[2];
    const float* Wg    = (const float*)d_in[3];
    const float* bg    = (const float*)d_in[4];
    const float* Wh    = (const float*)d_in[5];
    const float* bh    = (const float*)d_in[6];
    const float* gamma = (const float*)d_in[7];
    float* out = (float*)d_out;

    // ws (bf16): Kp (B*N*8) | Qp (B*N*8) | Vimg (B*N*64 image) = 5 MB
    unsigned short* Kp = (unsigned short*)d_ws;
    unsigned short* Qp = Kp + (size_t)BATCH * NPOS * CQK;
    unsigned short* Vimg = Qp + (size_t)BATCH * NPOS * CQK;

    dim3 pgrid(NPOS / 64, BATCH);
    proj_kernel<<<pgrid, 256, 0, stream>>>(x, Wf, bf, Wg, bg, Wh, bh, Kp, Qp, Vimg);

    attn_kernel<<<dim3(BATCH * NPOS / 64), 256, 0, stream>>>(Kp, Qp, Vimg, x, gamma, out);
}

// Round 9
// 40.208 us; speedup vs baseline: 1.0800x; 1.0800x over previous
//
#include <hip/hip_runtime.h>
#include <hip/hip_bf16.h>
#include <math.h>

// Problem constants
#define CIN 64
#define CQK 8
#define BATCH 8
#define NPOS 4096   // H*W
#define TN 128      // n-tile
#define NT (NPOS / TN)

typedef __attribute__((ext_vector_type(8))) short s16x8;
typedef __attribute__((ext_vector_type(4))) float f32x4;
typedef __attribute__((ext_vector_type(16))) float f32x16;

#define Z16 {0,0,0,0,0,0,0,0,0,0,0,0,0,0,0,0}

// single-instruction packed f32->bf16 (RNE) pair convert
__device__ inline unsigned cvt_pk_bf16(float lo, float hi) {
    unsigned r;
    asm("v_cvt_pk_bf16_f32 %0, %1, %2" : "=v"(r) : "v"(lo), "v"(hi));
    return r;
}

// ---------------------------------------------------------------------------
// Kernel 1: MFMA projections -> bf16 (validated round 7; unchanged).
//   One x-fragment pair serves BOTH as B-operand (KQ tile: A=W, D=[oc][n])
//   and as A-operand (V tiles: B=W, D=[n][C]) since A/B lane mappings of
//   mfma_f32_16x16x32_bf16 coincide (row/col=l&15, k=(l>>4)*8+e).
//   Outputs:
//     Kp[b,n,o] (o<8)           keys   (Wf + bf)
//     Qp[b,n,o] (o<8, *log2e)   queries(Wg + bg), pre-scaled for log2-domain
//     Vimg      values (Wh + bh) written DIRECTLY in the attention image
//               layout: piece p = ((j&1)*2+(C>>5))*64 + (j>>1)*32 + (C&31),
//               j = (h&1)*2 + (w&1), half = h>>1 (validated layout, round 6).
// Block = 256 thr (4 waves), 64 n; wave w owns n-group w*16..w*16+15.
// ---------------------------------------------------------------------------
__global__ __launch_bounds__(256) void proj_kernel(
    const float* __restrict__ x,
    const float* __restrict__ Wf, const float* __restrict__ bf,
    const float* __restrict__ Wg, const float* __restrict__ bg,
    const float* __restrict__ Wh, const float* __restrict__ bh,
    unsigned short* __restrict__ Kp, unsigned short* __restrict__ Qp,
    unsigned short* __restrict__ Vimg)
{
    __shared__ float xs[CIN * 66];   // 16.9 KB; stride 66 -> frag reads 2/bank
    __shared__ float bss[80];        // bf(8) | bg(8) | bh(64)

    const int tid = threadIdx.x;
    const int b   = blockIdx.y;
    const int n0  = blockIdx.x * 64;

    if (tid < 80)
        bss[tid] = (tid < 8) ? bf[tid] : (tid < 16) ? bg[tid - 8] : bh[tid - 16];

    // ---- stage x tile (64c x 64n f32), coalesced global, float2 LDS ----
    {
        const int c   = tid >> 2;
        const int seg = tid & 3;
        const float* src = x + ((size_t)(b * CIN + c)) * NPOS + n0 + seg * 16;
        float* dst = xs + c * 66 + seg * 16;
#pragma unroll
        for (int k = 0; k < 4; ++k) {
            const float4 v = *(const float4*)(src + k * 4);
            *(float2*)(dst + k * 4)     = make_float2(v.x, v.y);
            *(float2*)(dst + k * 4 + 2) = make_float2(v.z, v.w);
        }
    }

    const int l  = tid & 63;
    const int w  = tid >> 6;       // wave = n-group
    const int lm = l & 15;
    const int h  = l >> 4;

    auto wfrag = [&](const float* Wrow) -> s16x8 {
        const float4 a  = *(const float4*)(Wrow);
        const float4 bq = *(const float4*)(Wrow + 4);
        union { unsigned u[4]; s16x8 v; } r;
        r.u[0] = cvt_pk_bf16(a.x, a.y);
        r.u[1] = cvt_pk_bf16(a.z, a.w);
        r.u[2] = cvt_pk_bf16(bq.x, bq.y);
        r.u[3] = cvt_pk_bf16(bq.z, bq.w);
        return r.v;
    };

    const float* kqrow = (lm < 8) ? (Wf + lm * CIN) : (Wg + (lm - 8) * CIN);
    const s16x8 wkq0 = wfrag(kqrow + h * 8);
    const s16x8 wkq1 = wfrag(kqrow + h * 8 + 32);
    s16x8 wv0[4], wv1[4];
#pragma unroll
    for (int vt = 0; vt < 4; ++vt) {
        const float* vr = Wh + (vt * 16 + lm) * CIN + h * 8;
        wv0[vt] = wfrag(vr);
        wv1[vt] = wfrag(vr + 32);
    }

    __syncthreads();

    // ---- x fragments: col/row n = lm, k-slots c = h*8+e (+32 for half1) ----
    union { unsigned u[4]; s16x8 v; } xf0, xf1;
#pragma unroll
    for (int e2 = 0; e2 < 4; ++e2) {
        const int c = h * 8 + e2 * 2;
        xf0.u[e2] = cvt_pk_bf16(xs[c * 66 + w * 16 + lm],
                                xs[(c + 1) * 66 + w * 16 + lm]);
        xf1.u[e2] = cvt_pk_bf16(xs[(c + 32) * 66 + w * 16 + lm],
                                xs[(c + 33) * 66 + w * 16 + lm]);
    }

    // ---- 10 MFMAs: 1 KQ tile + 4 V tiles, 2 k-halves each ----
    const f32x4 z = {0.f, 0.f, 0.f, 0.f};
    f32x4 kq = __builtin_amdgcn_mfma_f32_16x16x32_bf16(wkq0, xf0.v, z, 0, 0, 0);
    kq = __builtin_amdgcn_mfma_f32_16x16x32_bf16(wkq1, xf1.v, kq, 0, 0, 0);
    f32x4 va[4];
#pragma unroll
    for (int vt = 0; vt < 4; ++vt) {
        va[vt] = __builtin_amdgcn_mfma_f32_16x16x32_bf16(xf0.v, wv0[vt], z, 0, 0, 0);
        va[vt] = __builtin_amdgcn_mfma_f32_16x16x32_bf16(xf1.v, wv1[vt], va[vt], 0, 0, 0);
    }

    const float LOG2E = 1.44269504088896f;

    // ---- K/Q epilogue: D[col=n=lm][row=oc=h*4+j]; rows 0-7 K, 8-15 Q ----
    {
        const int n = n0 + w * 16 + lm;
        float v0 = kq[0] + bss[h * 4 + 0];
        float v1 = kq[1] + bss[h * 4 + 1];
        float v2 = kq[2] + bss[h * 4 + 2];
        float v3 = kq[3] + bss[h * 4 + 3];
        if (h >= 2) { v0 *= LOG2E; v1 *= LOG2E; v2 *= LOG2E; v3 *= LOG2E; }
        uint2 pk;
        pk.x = cvt_pk_bf16(v0, v1);
        pk.y = cvt_pk_bf16(v2, v3);
        unsigned short* dstq =
            (h < 2 ? Kp : Qp) + ((size_t)(b * NPOS + n)) * CQK + (h & 1) * 4;
        *(uint2*)dstq = pk;
    }

    // ---- V epilogue: D[col=C][row-quad h = n-quad]; direct image stores ----
    {
        const int t128 = n0 >> 7;
        const int sub  = ((n0 & 127) >> 5) + (w >> 1);
        unsigned short* dstB =
            Vimg + ((size_t)(b * 32 + t128)) * 8192 + (size_t)sub * 2048;
        const int jj   = (h & 1) * 2 + (w & 1);
        const int half = h >> 1;
#pragma unroll
        for (int vt = 0; vt < 4; ++vt) {
            const int C = vt * 16 + lm;
            const float bb = bss[16 + C];
            uint2 pk;
            pk.x = cvt_pk_bf16(va[vt][0] + bb, va[vt][1] + bb);
            pk.y = cvt_pk_bf16(va[vt][2] + bb, va[vt][3] + bb);
            const int p = ((jj & 1) * 2 + (C >> 5)) * 64 + (jj >> 1) * 32 + (C & 31);
            *(uint2*)(dstB + p * 8 + half * 4) = pk;
        }
    }
}

// ---------------------------------------------------------------------------
// Kernel 2: MFMA flash attention, no-max unnormalized softmax, 32x32x16.
// ROUND 9: one-tile SCORE PIPELINE — each slot computes QK^T for tile t+1
// (no same-slot consumer) and runs exp/cvt/PV/rowsum on tile t's scores
// (inputs >= 1 slot old). Counted vmcnt(4): K(t+2) issued at slot start,
// V(t+2) at slot end -> steady 9 outstanding, oldest 5 (V(t)+K(t+1))
// retired by each wait. Row sums: in-lane 15-add tree (f32) + shfl_xor(32)
// instead of ones-MFMAs. No LDS in main loop.
// ---------------------------------------------------------------------------
__global__ __launch_bounds__(256, 2) void attn_kernel(
    const unsigned short* __restrict__ Kp, const unsigned short* __restrict__ Qp,
    const unsigned short* __restrict__ Vimg, const float* __restrict__ x,
    const float* __restrict__ gamma, float* __restrict__ out)
{
    // epilogue only: 4 wave-regions x 64C x 36 f32 + rsl[4][64]
    __shared__ __align__(16) float smem[4 * 64 * 36 + 256];
    float* reg = smem;
    float* rsl = smem + 4 * 64 * 36;

    const int tid = threadIdx.x;
    const int l   = tid & 63;
    const int w   = tid >> 6;      // wave = substep owner
    const int lc  = l & 31;
    const int h   = l >> 5;
    const int id  = blockIdx.x;
    const int b   = id & 7;        // XCD-pinned batch
    const int m0  = (id >> 3) * 64;

    const unsigned short* Kbat = Kp + (size_t)b * NPOS * CQK;
    const char* Vbat = (const char*)(Vimg + (size_t)b * NPOS * CIN);

    // Q fragments (B operand): h=1 lanes (k=8..15) must be zero
    s16x8 qf0 = {0,0,0,0,0,0,0,0}, qf1 = {0,0,0,0,0,0,0,0};
    if (h == 0) {
        qf0 = *(const s16x8*)(Qp + ((size_t)(b * NPOS + m0 + lc)) * CQK);
        qf1 = *(const s16x8*)(Qp + ((size_t)(b * NPOS + m0 + 32 + lc)) * CQK);
    }

    f32x16 acc00 = Z16, acc01 = Z16, acc10 = Z16, acc11 = Z16;
    float rsum0 = 0.f, rsum1 = 0.f;

    s16x8 vfA[4], vfB[4], kaA, kaB;
    f32x16 scA0, scA1, scB0, scB1;
    const f32x16 z = Z16;

    auto loadV = [&](s16x8* vf, int t) {
        const char* base = Vbat + (size_t)t * 16384 + w * 4096 + l * 16;
#pragma unroll
        for (int c = 0; c < 4; ++c)
            vf[c] = *(const s16x8*)(base + c * 1024);
    };
    auto loadK = [&](s16x8& kr, int t) {
        kr = *(const s16x8*)(Kbat + ((size_t)(t * TN + w * 32 + lc)) * CQK);
    };

    // exp/cvt/PV/rowsum on one tile's scores (consumes s0,s1 in place)
    auto proc = [&](f32x16& s0, f32x16& s1, const s16x8* vf) {
        __builtin_amdgcn_s_setprio(1);
        // ---- m-tile 0 ----
#pragma unroll
        for (int rr = 0; rr < 16; ++rr) s0[rr] = __builtin_amdgcn_exp2f(s0[rr]);
        union { unsigned u[4]; s16x8 v; } A1, A2;
#pragma unroll
        for (int i = 0; i < 4; ++i) {
            A1.u[i] = cvt_pk_bf16(s0[2 * i], s0[2 * i + 1]);
            A2.u[i] = cvt_pk_bf16(s0[8 + 2 * i], s0[9 + 2 * i]);
        }
        rsum0 += (((s0[0] + s0[1]) + (s0[2] + s0[3])) +
                  ((s0[4] + s0[5]) + (s0[6] + s0[7]))) +
                 (((s0[8] + s0[9]) + (s0[10] + s0[11])) +
                  ((s0[12] + s0[13]) + (s0[14] + s0[15])));
        acc00 = __builtin_amdgcn_mfma_f32_32x32x16_bf16(A1.v, vf[0], acc00, 0, 0, 0);
        acc00 = __builtin_amdgcn_mfma_f32_32x32x16_bf16(A2.v, vf[2], acc00, 0, 0, 0);
        acc01 = __builtin_amdgcn_mfma_f32_32x32x16_bf16(A1.v, vf[1], acc01, 0, 0, 0);
        acc01 = __builtin_amdgcn_mfma_f32_32x32x16_bf16(A2.v, vf[3], acc01, 0, 0, 0);
        // ---- m-tile 1 ----
#pragma unroll
        for (int rr = 0; rr < 16; ++rr) s1[rr] = __builtin_amdgcn_exp2f(s1[rr]);
        union { unsigned u[4]; s16x8 v; } B1, B2;
#pragma unroll
        for (int i = 0; i < 4; ++i) {
            B1.u[i] = cvt_pk_bf16(s1[2 * i], s1[2 * i + 1]);
            B2.u[i] = cvt_pk_bf16(s1[8 + 2 * i], s1[9 + 2 * i]);
        }
        rsum1 += (((s1[0] + s1[1]) + (s1[2] + s1[3])) +
                  ((s1[4] + s1[5]) + (s1[6] + s1[7]))) +
                 (((s1[8] + s1[9]) + (s1[10] + s1[11])) +
                  ((s1[12] + s1[13]) + (s1[14] + s1[15])));
        acc10 = __builtin_amdgcn_mfma_f32_32x32x16_bf16(B1.v, vf[0], acc10, 0, 0, 0);
        acc10 = __builtin_amdgcn_mfma_f32_32x32x16_bf16(B2.v, vf[2], acc10, 0, 0, 0);
        acc11 = __builtin_amdgcn_mfma_f32_32x32x16_bf16(B1.v, vf[1], acc11, 0, 0, 0);
        acc11 = __builtin_amdgcn_mfma_f32_32x32x16_bf16(B2.v, vf[3], acc11, 0, 0, 0);
        __builtin_amdgcn_s_setprio(0);
    };

    // ---- prologue: tiles 0,1 in flight; scores for tile 0 ----
    loadK(kaA, 0); loadV(vfA, 0);
    loadK(kaB, 1); loadV(vfB, 1);
    asm volatile("s_waitcnt vmcnt(5)" ::: "memory");   // K0+V0 done
    scA0 = __builtin_amdgcn_mfma_f32_32x32x16_bf16(kaA, qf0, z, 0, 0, 0);
    scA1 = __builtin_amdgcn_mfma_f32_32x32x16_bf16(kaA, qf1, z, 0, 0, 0);

#pragma unroll 1
    for (int t = 0; t < NT - 2; t += 2) {
        // ---- slot A: consume tile t; produce scores for t+1 ----
        asm volatile("s_waitcnt vmcnt(4)" ::: "memory");  // V(t)+K(t+1) done
        scB0 = __builtin_amdgcn_mfma_f32_32x32x16_bf16(kaB, qf0, z, 0, 0, 0);
        scB1 = __builtin_amdgcn_mfma_f32_32x32x16_bf16(kaB, qf1, z, 0, 0, 0);
        loadK(kaA, t + 2);
        proc(scA0, scA1, vfA);
        loadV(vfA, t + 2);
        // ---- slot B: consume tile t+1; produce scores for t+2 ----
        asm volatile("s_waitcnt vmcnt(4)" ::: "memory");  // V(t+1)+K(t+2) done
        scA0 = __builtin_amdgcn_mfma_f32_32x32x16_bf16(kaA, qf0, z, 0, 0, 0);
        scA1 = __builtin_amdgcn_mfma_f32_32x32x16_bf16(kaA, qf1, z, 0, 0, 0);
        loadK(kaB, t + 3);
        proc(scB0, scB1, vfB);
        loadV(vfB, t + 3);
    }
    // ---- peeled tail: tiles NT-2, NT-1 ----
    asm volatile("s_waitcnt vmcnt(4)" ::: "memory");
    scB0 = __builtin_amdgcn_mfma_f32_32x32x16_bf16(kaB, qf0, z, 0, 0, 0);
    scB1 = __builtin_amdgcn_mfma_f32_32x32x16_bf16(kaB, qf1, z, 0, 0, 0);
    proc(scA0, scA1, vfA);
    asm volatile("s_waitcnt vmcnt(0)" ::: "memory");
    proc(scB0, scB1, vfB);

    // ---- combine row-sum partials across lane halves, publish to LDS ----
    rsum0 += __shfl_xor(rsum0, 32, 64);
    rsum1 += __shfl_xor(rsum1, 32, 64);
    if (h == 0) {
        rsl[w * 64 + lc]      = rsum0;
        rsl[w * 64 + 32 + lc] = rsum1;
    }

    // ---- two-phase epilogue: combine wave partials per m-tile ----
    const float gm = gamma[0];
    auto epi = [&](const f32x16& a0, const f32x16& a1, int mOff) {
#pragma unroll
        for (int rq = 0; rq < 4; ++rq) {
            const int mb = 8 * rq + 4 * h;
            const f32x4 q0 = {a0[4 * rq], a0[4 * rq + 1], a0[4 * rq + 2], a0[4 * rq + 3]};
            const f32x4 q1 = {a1[4 * rq], a1[4 * rq + 1], a1[4 * rq + 2], a1[4 * rq + 3]};
            *(f32x4*)(reg + w * 2304 + lc * 36 + mb)        = q0;  // C = lc
            *(f32x4*)(reg + w * 2304 + (32 + lc) * 36 + mb) = q1;  // C = 32+lc
        }
        __syncthreads();
        const int c  = tid >> 2;
        const int mq = tid & 3;
        const size_t base = ((size_t)(b * CIN + c)) * NPOS + m0 + mOff + mq * 8;
#pragma unroll
        for (int q4 = 0; q4 < 2; ++q4) {
            const float4 xv = *(const float4*)(x + base + q4 * 4);
            float4 o;
#pragma unroll
            for (int i = 0; i < 4; ++i) {
                const int ml = mq * 8 + q4 * 4 + i;
                const float rsum = (rsl[mOff + ml] + rsl[64 + mOff + ml]) +
                                   (rsl[128 + mOff + ml] + rsl[192 + mOff + ml]);
                const int oi = c * 36 + ml;
                const float os = (reg[oi] + reg[2304 + oi]) + (reg[4608 + oi] + reg[6912 + oi]);
                ((float*)&o)[i] = ((const float*)&xv)[i] + gm * os / rsum;
            }
            *(float4*)(out + base + q4 * 4) = o;
        }
        __syncthreads();
    };
    epi(acc00, acc01, 0);
    epi(acc10, acc11, 32);
}

extern "C" void kernel_launch(void* const* d_in, const int* in_sizes, int n_in,
                              void* d_out, int out_size, void* d_ws, size_t ws_size,
                              hipStream_t stream) {
    const float* x     = (const float*)d_in[0];
    const float* Wf    = (const float*)d_in[1];
    const float* bf    = (const float*)d_in[2];
    const float* Wg    = (const float*)d_in[3];
    const float* bg    = (const float*)d_in[4];
    const float* Wh    = (const float*)d_in[5];
    const float* bh    = (const float*)d_in[6];
    const float* gamma = (const float*)d_in[7];
    float* out = (float*)d_out;

    // ws (bf16): Kp (B*N*8) | Qp (B*N*8) | Vimg (B*N*64 image) = 5 MB
    unsigned short* Kp = (unsigned short*)d_ws;
    unsigned short* Qp = Kp + (size_t)BATCH * NPOS * CQK;
    unsigned short* Vimg = Qp + (size_t)BATCH * NPOS * CQK;

    dim3 pgrid(NPOS / 64, BATCH);
    proj_kernel<<<pgrid, 256, 0, stream>>>(x, Wf, bf, Wg, bg, Wh, bh, Kp, Qp, Vimg);

    attn_kernel<<<dim3(BATCH * NPOS / 64), 256, 0, stream>>>(Kp, Qp, Vimg, x, gamma, out);
}